// Round 18
// baseline (196.104 us; speedup 1.0000x reference)
//
#include <hip/hip_runtime.h>
#include <cstdint>
#include <cstddef>

typedef __attribute__((ext_vector_type(8))) __bf16 bf16x8;
typedef __attribute__((ext_vector_type(4))) __bf16 bf16x4;
typedef __attribute__((ext_vector_type(4))) float f32x4;
typedef __attribute__((ext_vector_type(16))) float f32x16;
typedef __attribute__((ext_vector_type(4))) unsigned uint4v;

#define B_ 4
#define T_ 2048
#define C_ 1024
#define H_ 16
#define D_ 64
#define NTILES_ (T_ / 32)
#define TILE_ELEMS_ 2048
#define BH_STRIDE_ ((size_t)NTILES_ * TILE_ELEMS_)  // 131072

__device__ __forceinline__ float fexp2(float x) {
#if __has_builtin(__builtin_amdgcn_exp2f)
  return __builtin_amdgcn_exp2f(x);
#else
  return __expf(x * 0.69314718f);
#endif
}

// ---------------------------------------------------------------- fused cast f32->bf16
__global__ __launch_bounds__(256) void castall(
    const float* __restrict__ x, const float* __restrict__ wq, const float* __restrict__ wk,
    const float* __restrict__ wv, const float* __restrict__ wp,
    __bf16* __restrict__ xb, __bf16* __restrict__ wqb, __bf16* __restrict__ wkb,
    __bf16* __restrict__ wvb, __bf16* __restrict__ wpb) {
  const int bid = blockIdx.x;
  const float* src;
  __bf16* dst;
  if (bid < 8192)       { src = x  + (size_t)bid * 1024;           dst = xb  + (size_t)bid * 1024; }
  else if (bid < 9216)  { src = wq + (size_t)(bid - 8192) * 1024;  dst = wqb + (size_t)(bid - 8192) * 1024; }
  else if (bid < 10240) { src = wk + (size_t)(bid - 9216) * 1024;  dst = wkb + (size_t)(bid - 9216) * 1024; }
  else if (bid < 11264) { src = wv + (size_t)(bid - 10240) * 1024; dst = wvb + (size_t)(bid - 10240) * 1024; }
  else                  { src = wp + (size_t)(bid - 11264) * 1024; dst = wpb + (size_t)(bid - 11264) * 1024; }
  const int i = threadIdx.x * 4;
  float4 f = *reinterpret_cast<const float4*>(src + i);
  bf16x4 o;
  o[0] = (__bf16)f.x; o[1] = (__bf16)f.y; o[2] = (__bf16)f.z; o[3] = (__bf16)f.w;
  *reinterpret_cast<bf16x4*>(dst + i) = o;
}

// ---------------------------------------------------------------- async global->LDS
__device__ __forceinline__ void gload_lds16(const __bf16* g, __bf16* lds) {
  __builtin_amdgcn_global_load_lds(
      (const __attribute__((address_space(1))) void*)g,
      (__attribute__((address_space(3))) void*)lds, 16, 0, 0);
}

// ---------------------------------------------------------------- 8-phase GEMM, BM=256 x BN=128 (R12-proven)
#define ST_A41(BUFO, KT, HH)                                                          \
  do {                                                                                \
    const __bf16* s0_ = Agp + (size_t)(m0 + (HH) * 128 + srow) * 1024 + (KT) * 64 + sswz; \
    gload_lds16(s0_, LDSb + (BUFO) + (HH) * 8192 + w * 1024);                         \
    gload_lds16(s0_ + 8 * 1024, LDSb + (BUFO) + (HH) * 8192 + w * 1024 + 512);        \
  } while (0)
#define ST_B41(BUFO, KT)                                                              \
  do {                                                                                \
    const __bf16* s0_ = Bgp + (size_t)(n0 + srow) * 1024 + (KT) * 64 + sswz;          \
    gload_lds16(s0_, LDSb + 32768 + (BUFO) + w * 1024);                               \
    gload_lds16(s0_ + 8 * 1024, LDSb + 32768 + (BUFO) + w * 1024 + 512);              \
  } while (0)
#define RDA41(M, KK) (*reinterpret_cast<const bf16x8*>(                               \
    LDSb + bufoA + (wr * 64 + (M) * 16 + lr) * 64 + (((KK) * 32 + lg * 8) ^ ((lr & 7) * 8))))
#define RDB41(N, KK) (*reinterpret_cast<const bf16x8*>(                               \
    LDSb + 32768 + bufoB + (wc * 64 + (N) * 16 + lr) * 64 + (((KK) * 32 + lg * 8) ^ ((lr & 7) * 8))))

#define GEMM8_KLOOP_41                                                                \
  ST_A41(0, 0, 0); ST_A41(0, 0, 1); ST_B41(0, 0);                                     \
  __builtin_amdgcn_sched_barrier(0);                                                  \
  asm volatile("s_waitcnt vmcnt(0)" ::: "memory");                                    \
  __builtin_amdgcn_s_barrier();                                                       \
  __builtin_amdgcn_sched_barrier(0);                                                  \
  for (int t = 0; t < 16; ++t) {                                                      \
    const int bufoA = (t & 1) * 16384;                                                \
    const int bufoB = (t & 1) * 8192;                                                 \
    const int nboA = ((t + 1) & 1) * 16384;                                           \
    const int nboB = ((t + 1) & 1) * 8192;                                            \
    const bool st = t < 15;                                                           \
    afA[0][0] = RDA41(0, 0); afA[0][1] = RDA41(0, 1);                                 \
    afA[1][0] = RDA41(1, 0); afA[1][1] = RDA41(1, 1);                                 \
    bfA[0][0] = RDB41(0, 0); bfA[0][1] = RDB41(0, 1);                                 \
    bfA[1][0] = RDB41(1, 0); bfA[1][1] = RDB41(1, 1);                                 \
    if (st) ST_A41(nboA, t + 1, 0);                                                   \
    __builtin_amdgcn_s_setprio(1);                                                    \
    _Pragma("unroll")                                                                 \
    for (int kk = 0; kk < 2; ++kk)                                                    \
      _Pragma("unroll")                                                               \
      for (int m = 0; m < 2; ++m) {                                                   \
        acc[m][0] = __builtin_amdgcn_mfma_f32_16x16x32_bf16(afA[m][kk], bfA[0][kk], acc[m][0], 0, 0, 0); \
        acc[m][1] = __builtin_amdgcn_mfma_f32_16x16x32_bf16(afA[m][kk], bfA[1][kk], acc[m][1], 0, 0, 0); \
      }                                                                               \
    __builtin_amdgcn_s_setprio(0);                                                    \
    __builtin_amdgcn_s_barrier();                                                     \
    bfB[0][0] = RDB41(2, 0); bfB[0][1] = RDB41(2, 1);                                 \
    bfB[1][0] = RDB41(3, 0); bfB[1][1] = RDB41(3, 1);                                 \
    if (st) ST_A41(nboA, t + 1, 1);                                                   \
    __builtin_amdgcn_s_setprio(1);                                                    \
    _Pragma("unroll")                                                                 \
    for (int kk = 0; kk < 2; ++kk)                                                    \
      _Pragma("unroll")                                                               \
      for (int m = 0; m < 2; ++m) {                                                   \
        acc[m][2] = __builtin_amdgcn_mfma_f32_16x16x32_bf16(afA[m][kk], bfB[0][kk], acc[m][2], 0, 0, 0); \
        acc[m][3] = __builtin_amdgcn_mfma_f32_16x16x32_bf16(afA[m][kk], bfB[1][kk], acc[m][3], 0, 0, 0); \
      }                                                                               \
    __builtin_amdgcn_s_setprio(0);                                                    \
    __builtin_amdgcn_s_barrier();                                                     \
    afB[0][0] = RDA41(2, 0); afB[0][1] = RDA41(2, 1);                                 \
    afB[1][0] = RDA41(3, 0); afB[1][1] = RDA41(3, 1);                                 \
    if (st) ST_B41(nboB, t + 1);                                                      \
    __builtin_amdgcn_s_setprio(1);                                                    \
    _Pragma("unroll")                                                                 \
    for (int kk = 0; kk < 2; ++kk)                                                    \
      _Pragma("unroll")                                                               \
      for (int m = 0; m < 2; ++m) {                                                   \
        acc[m + 2][0] = __builtin_amdgcn_mfma_f32_16x16x32_bf16(afB[m][kk], bfA[0][kk], acc[m + 2][0], 0, 0, 0); \
        acc[m + 2][1] = __builtin_amdgcn_mfma_f32_16x16x32_bf16(afB[m][kk], bfA[1][kk], acc[m + 2][1], 0, 0, 0); \
      }                                                                               \
    __builtin_amdgcn_s_setprio(0);                                                    \
    __builtin_amdgcn_s_barrier();                                                     \
    __builtin_amdgcn_s_setprio(1);                                                    \
    _Pragma("unroll")                                                                 \
    for (int kk = 0; kk < 2; ++kk)                                                    \
      _Pragma("unroll")                                                               \
      for (int m = 0; m < 2; ++m) {                                                   \
        acc[m + 2][2] = __builtin_amdgcn_mfma_f32_16x16x32_bf16(afB[m][kk], bfB[0][kk], acc[m + 2][2], 0, 0, 0); \
        acc[m + 2][3] = __builtin_amdgcn_mfma_f32_16x16x32_bf16(afB[m][kk], bfB[1][kk], acc[m + 2][3], 0, 0, 0); \
      }                                                                               \
    __builtin_amdgcn_s_setprio(0);                                                    \
    __builtin_amdgcn_sched_barrier(0);                                                \
    asm volatile("s_waitcnt vmcnt(0)" ::: "memory");                                  \
    __builtin_amdgcn_s_barrier();                                                     \
    __builtin_amdgcn_sched_barrier(0);                                                \
  }

// ---------------------------------------------------------------- fused QKV GEMM (256x128, 768 blocks)
__global__ __launch_bounds__(512, 2) void gemm_qkv8(
    const __bf16* __restrict__ Agp, const __bf16* __restrict__ Bgp,
    __bf16* __restrict__ qf, __bf16* __restrict__ kf, __bf16* __restrict__ vf) {
  __shared__ __bf16 LDSb[49152];
  const int tid = threadIdx.x;
  const int w = tid >> 6, l = tid & 63;
  const int wr = w >> 1, wc = w & 1;
  const int lr = l & 15, lg = l >> 4;
  int lin = blockIdx.y * 24 + blockIdx.x;
  lin = (lin & 7) * 96 + (lin >> 3);
  const int bx = lin % 24, by = lin / 24;
  const int m0 = by * 256, n0 = bx * 128;
  const int srow = w * 16 + (l >> 3);
  const int sswz = ((l & 7) ^ ((l >> 3) & 7)) * 8;

  f32x4 acc[4][4] = {};
  bf16x8 afA[2][2], afB[2][2], bfA[2][2], bfB[2][2];

  GEMM8_KLOOP_41

  __bf16* wl = LDSb + w * 4096;
  const int colb = n0 + wc * 64;
  const int mat = colb >> 10;
  const int h = (colb >> 6) & 15;
  const int b = m0 >> 11;
  const float qsc = (mat == 0) ? 0.04508422f : 1.0f;  // C^-0.5 * log2(e)
#pragma unroll
  for (int mi = 0; mi < 4; ++mi) {
    const int rt = mi >> 1;
#pragma unroll
    for (int n = 0; n < 4; ++n) {
      const int d = n * 16 + lr;
#pragma unroll
      for (int j = 0; j < 4; ++j) {
        const int rowloc = (mi & 1) * 16 + lg * 4 + j;
        int off;
        if (mat < 2)
          off = ((d >> 4) & 3) * 512 + ((d >> 3) & 1) * 256 + rowloc * 8 + (d & 7);
        else
          off = (d >> 5) * 1024 + ((rowloc >> 4) & 1) * 512 + ((rowloc >> 3) & 1) * 256 +
                (d & 31) * 8 + (rowloc & 7);
        wl[rt * 2048 + off] = (__bf16)(acc[mi][n][j] * qsc);
      }
    }
  }
  __bf16* dstbase = (mat == 0 ? qf : mat == 1 ? kf : vf) + (size_t)(b * 16 + h) * BH_STRIDE_;
  const int rt0 = ((m0 + wr * 64) >> 5) & 63;
#pragma unroll
  for (int rt = 0; rt < 2; ++rt)
#pragma unroll
    for (int c = 0; c < 4; ++c) {
      const bf16x8 vchunk = *reinterpret_cast<const bf16x8*>(wl + rt * 2048 + c * 512 + l * 8);
      *reinterpret_cast<bf16x8*>(dstbase + (size_t)(rt0 + rt) * TILE_ELEMS_ + c * 512 + l * 8) = vchunk;
    }
}

// ---------------------------------------------------------------- proj GEMM (256x128, 256 blocks)
__global__ __launch_bounds__(512, 2) void gemm_proj8(
    const __bf16* __restrict__ Agp, const __bf16* __restrict__ Bgp,
    float* __restrict__ out, const float* __restrict__ bias) {
  __shared__ __bf16 LDSb[49152];
  const int tid = threadIdx.x;
  const int w = tid >> 6, l = tid & 63;
  const int wr = w >> 1, wc = w & 1;
  const int lr = l & 15, lg = l >> 4;
  int lin = blockIdx.y * 8 + blockIdx.x;
  lin = (lin & 7) * 32 + (lin >> 3);
  const int bx = lin & 7, by = lin >> 3;
  const int m0 = by * 256, n0 = bx * 128;
  const int srow = w * 16 + (l >> 3);
  const int sswz = ((l & 7) ^ ((l >> 3) & 7)) * 8;

  f32x4 acc[4][4] = {};
  bf16x8 afA[2][2], afB[2][2], bfA[2][2], bfB[2][2];

  GEMM8_KLOOP_41

  const int colb = n0 + wc * 64;
#pragma unroll
  for (int mi = 0; mi < 4; ++mi) {
    const int row = m0 + wr * 64 + mi * 16 + lg * 4;
#pragma unroll
    for (int n = 0; n < 4; ++n) {
      const int col = colb + n * 16 + lr;
      const float bv = bias[col];
#pragma unroll
      for (int j = 0; j < 4; ++j)
        out[(size_t)(row + j) * 1024 + col] = acc[mi][n][j] + bv;
    }
  }
}

// ---------------------------------------------------------------- helpers
__device__ __forceinline__ unsigned pk2(float a, float b) {
  const unsigned short ua = __builtin_bit_cast(unsigned short, (__bf16)a);
  const unsigned short ub = __builtin_bit_cast(unsigned short, (__bf16)b);
  return (unsigned)ua | ((unsigned)ub << 16);
}

// P^T word exchange (R14-verified): permlane32_swap(X, Y) -> {w0, w2}.
__device__ __forceinline__ void exch2(unsigned X, unsigned Y, int hi,
                                      unsigned& w0, unsigned& w2) {
#if __has_builtin(__builtin_amdgcn_permlane32_swap)
  auto r = __builtin_amdgcn_permlane32_swap(X, Y, false, false);
  w0 = r[0];
  w2 = r[1];
#else
  const unsigned sX = __shfl_xor(X, 32);
  const unsigned sY = __shfl_xor(Y, 32);
  w0 = hi ? sY : X;
  w2 = hi ? Y : sX;
#endif
}

// ---------------------------------------------------------------- flash attention v16
// R16 structure + 2-deep pipeline, with BOTH prior failure modes fixed:
//   - R15's spill: no launch-bounds VGPR cap (grid fixes 2 waves/SIMD; ~180 VGPR ok)
//   - R17's V exposure: K AND V double-buffered; V(j+2) loaded AFTER SOFTPV(j)
//     (no WAR on vA; ~2 iterations of latency cover), K(j+2) at iteration top
//     (kA dead since iter j-1; 1 full iteration of cover).
// Iteration j: QKT(t=j+1) MFMAs issue FIRST; softmax+PV(t=j) runs underneath.
#define LOADK(SFX, TT)                                                           \
  do {                                                                           \
    const __bf16* kp_ = kfb + (size_t)(TT) * TILE_ELEMS_ + lx8;                  \
    k##SFX##0 = *reinterpret_cast<const bf16x8*>(kp_);                           \
    k##SFX##1 = *reinterpret_cast<const bf16x8*>(kp_ + 512);                     \
    k##SFX##2 = *reinterpret_cast<const bf16x8*>(kp_ + 1024);                    \
    k##SFX##3 = *reinterpret_cast<const bf16x8*>(kp_ + 1536);                    \
  } while (0)
#define LOADV(SFX, TT)                                                           \
  do {                                                                           \
    const __bf16* vp_ = vfb + (size_t)(TT) * TILE_ELEMS_ + lx8;                  \
    v##SFX##0 = *reinterpret_cast<const bf16x8*>(vp_);                           \
    v##SFX##1 = *reinterpret_cast<const bf16x8*>(vp_ + 512);                     \
    v##SFX##2 = *reinterpret_cast<const bf16x8*>(vp_ + 1024);                    \
    v##SFX##3 = *reinterpret_cast<const bf16x8*>(vp_ + 1536);                    \
  } while (0)
#define QKT(SD, SFX)                                                             \
  do {                                                                           \
    _Pragma("unroll") for (int r = 0; r < 16; ++r) SD[r] = 0.f;                  \
    SD = __builtin_amdgcn_mfma_f32_32x32x16_bf16(k##SFX##0, qf[0], SD, 0, 0, 0); \
    SD = __builtin_amdgcn_mfma_f32_32x32x16_bf16(k##SFX##1, qf[1], SD, 0, 0, 0); \
    SD = __builtin_amdgcn_mfma_f32_32x32x16_bf16(k##SFX##2, qf[2], SD, 0, 0, 0); \
    SD = __builtin_amdgcn_mfma_f32_32x32x16_bf16(k##SFX##3, qf[3], SD, 0, 0, 0); \
  } while (0)
#define SOFTPV(SD, VSFX, MASKED)                                                 \
  do {                                                                           \
    if (MASKED) {                                                                \
      _Pragma("unroll") for (int r = 0; r < 16; ++r) {                           \
        const int kvloc = (r & 3) + 8 * (r >> 2) + 4 * hi;                       \
        SD[r] = (kvloc <= lane31) ? SD[r] : -1e30f;                              \
      }                                                                          \
    }                                                                            \
    _Pragma("unroll") for (int r = 0; r < 16; ++r) SD[r] = fexp2(SD[r]);         \
    unsigned pwv[8];                                                             \
    _Pragma("unroll") for (int ks = 0; ks < 2; ++ks) {                           \
      const unsigned X0 = pk2(SD[ks * 8 + 0], SD[ks * 8 + 1]);                   \
      const unsigned X1 = pk2(SD[ks * 8 + 2], SD[ks * 8 + 3]);                   \
      const unsigned Y0 = pk2(SD[ks * 8 + 4], SD[ks * 8 + 5]);                   \
      const unsigned Y1 = pk2(SD[ks * 8 + 6], SD[ks * 8 + 7]);                   \
      exch2(X0, Y0, hi, pwv[ks * 4 + 0], pwv[ks * 4 + 2]);                       \
      exch2(X1, Y1, hi, pwv[ks * 4 + 1], pwv[ks * 4 + 3]);                       \
    }                                                                            \
    const uint4v u0 = {pwv[0], pwv[1], pwv[2], pwv[3]};                          \
    const uint4v u1 = {pwv[4], pwv[5], pwv[6], pwv[7]};                          \
    const bf16x8 pf0 = __builtin_bit_cast(bf16x8, u0);                           \
    const bf16x8 pf1 = __builtin_bit_cast(bf16x8, u1);                           \
    acc0 = __builtin_amdgcn_mfma_f32_32x32x16_bf16(v##VSFX##0, pf0, acc0, 0, 0, 0); \
    acc0 = __builtin_amdgcn_mfma_f32_32x32x16_bf16(v##VSFX##1, pf1, acc0, 0, 0, 0); \
    acc1 = __builtin_amdgcn_mfma_f32_32x32x16_bf16(v##VSFX##2, pf0, acc1, 0, 0, 0); \
    acc1 = __builtin_amdgcn_mfma_f32_32x32x16_bf16(v##VSFX##3, pf1, acc1, 0, 0, 0); \
    float b8[8];                                                                 \
    _Pragma("unroll") for (int r = 0; r < 8; ++r) b8[r] = SD[2 * r] + SD[2 * r + 1]; \
    _Pragma("unroll") for (int r = 0; r < 4; ++r) b8[r] = b8[2 * r] + b8[2 * r + 1]; \
    l_run += (b8[0] + b8[1]) + (b8[2] + b8[3]);                                  \
  } while (0)

__global__ __launch_bounds__(256) void attn_fwd(const __bf16* __restrict__ qfr,
                                                const __bf16* __restrict__ kfr,
                                                const __bf16* __restrict__ vfr,
                                                __bf16* __restrict__ ao) {
  const int tid = threadIdx.x;
  const int w = tid >> 6, l = tid & 63;
  const int lane31 = l & 31, hi = l >> 5;
  const int bh = blockIdx.x & 63;   // XCD affinity (R11-proven)
  const int qi = blockIdx.x >> 6;   // 0..7
  const int b = bh >> 4;
  const int qx = qi * 4 + w;        // 0..31; paired with 63-qx => 65 tiles/wave
  const size_t rowbase = (size_t)b * T_;
  const int hoff = (bh & 15) * D_;
  const int lx8 = l * 8;
  const __bf16* qfb = qfr + (size_t)bh * BH_STRIDE_;
  const __bf16* kfb = kfr + (size_t)bh * BH_STRIDE_;
  const __bf16* vfb = vfr + (size_t)bh * BH_STRIDE_;

  for (int phase = 0; phase < 2; ++phase) {
    const int qg = (phase ? 63 - qx : qx) * 32;
    const int nt = (qg >> 5) + 1;

    bf16x8 qf[4];
    {
      const __bf16* qp = qfb + (size_t)(qg >> 5) * TILE_ELEMS_ + lx8;
#pragma unroll
      for (int t4 = 0; t4 < 4; ++t4) qf[t4] = *reinterpret_cast<const bf16x8*>(qp + t4 * 512);
    }

    f32x16 acc0 = {};
    f32x16 acc1 = {};
    float l_run = 0.f;

    bf16x8 kA0, kA1, kA2, kA3, vA0, vA1, vA2, vA3;
    bf16x8 kB0, kB1, kB2, kB3, vB0, vB1, vB2, vB3;
    f32x16 sA, sB;

    // prologue
    LOADK(A, 0);
    LOADV(A, 0);
    if (nt > 1) LOADK(B, 1);
    QKT(sA, A);
    if (nt > 1) LOADV(B, 1);

    int j = 0;
    for (; j + 1 < nt; ++j) {
      if ((j & 1) == 0) {
        if (j + 2 < nt) LOADK(A, j + 2);   // kA dead since iter j-1; 1-iter cover
        QKT(sB, B);                        // MFMAs for tile j+1 issue first
        SOFTPV(sA, A, false);              // softmax(j) under them; PV(j) uses vA
        if (j + 2 < nt) LOADV(A, j + 2);   // vA dead after PV(j); ~2-iter cover
      } else {
        if (j + 2 < nt) LOADK(B, j + 2);
        QKT(sA, A);
        SOFTPV(sB, B, false);
        if (j + 2 < nt) LOADV(B, j + 2);
      }
    }
    if ((j & 1) == 0) SOFTPV(sA, A, true);
    else              SOFTPV(sB, B, true);

    // combine the two kv-halves held by partner lanes
    l_run += __shfl_xor(l_run, 32);

    // epilogue: O[q][d] = O^T[d][q]/l ; d = dblk*32 + qd*8 + hi*4 + j
    const float rl = 1.0f / l_run;
    __bf16* op = ao + (rowbase + qg + lane31) * C_ + hoff + hi * 4;
#pragma unroll
    for (int dblk = 0; dblk < 2; ++dblk)
#pragma unroll
      for (int qd = 0; qd < 4; ++qd) {
        bf16x4 ov;
#pragma unroll
        for (int j2 = 0; j2 < 4; ++j2) {
          const float av = (dblk == 0) ? acc0[qd * 4 + j2] : acc1[qd * 4 + j2];
          ov[j2] = (__bf16)(av * rl);
        }
        *reinterpret_cast<bf16x4*>(op + dblk * 32 + qd * 8) = ov;
      }
  }
}

// ---------------------------------------------------------------- launch
extern "C" void kernel_launch(void* const* d_in, const int* in_sizes, int n_in,
                              void* d_out, int out_size, void* d_ws, size_t ws_size,
                              hipStream_t stream) {
  const float* x  = (const float*)d_in[0];
  const float* Wq = (const float*)d_in[1];
  const float* Wk = (const float*)d_in[2];
  const float* Wv = (const float*)d_in[3];
  const float* Wp = (const float*)d_in[4];
  const float* bp = (const float*)d_in[5];
  float* out = (float*)d_out;

  const int NX = B_ * T_ * C_;
  const int NW = C_ * C_;

  __bf16* xb  = (__bf16*)d_ws;
  __bf16* wqb = xb + NX;
  __bf16* wkb = wqb + NW;
  __bf16* wvb = wkb + NW;
  __bf16* wpb = wvb + NW;
  __bf16* qf  = wpb + NW;
  __bf16* kf  = qf + NX;
  __bf16* vf  = kf + NX;
  __bf16* aob = xb;  // xb dead after gemm_qkv8

  castall<<<12288, 256, 0, stream>>>(x, Wq, Wk, Wv, Wp, xb, wqb, wkb, wvb, wpb);

  gemm_qkv8<<<dim3(24, 32), 512, 0, stream>>>(xb, wqb, qf, kf, vf);
  attn_fwd<<<512, 256, 0, stream>>>(qf, kf, vf, aob);
  gemm_proj8<<<dim3(8, 32), 512, 0, stream>>>(aob, wpb, out, bp);
}

// Round 19
// 157.223 us; speedup vs baseline: 1.2473x; 1.2473x over previous
//
#include <hip/hip_runtime.h>
#include <cstdint>
#include <cstddef>

typedef __attribute__((ext_vector_type(8))) __bf16 bf16x8;
typedef __attribute__((ext_vector_type(4))) __bf16 bf16x4;
typedef __attribute__((ext_vector_type(4))) float f32x4;
typedef __attribute__((ext_vector_type(16))) float f32x16;
typedef __attribute__((ext_vector_type(4))) unsigned uint4v;

#define B_ 4
#define T_ 2048
#define C_ 1024
#define H_ 16
#define D_ 64
#define NTILES_ (T_ / 32)
#define TILE_ELEMS_ 2048
#define BH_STRIDE_ ((size_t)NTILES_ * TILE_ELEMS_)  // 131072

__device__ __forceinline__ float fexp2(float x) {
#if __has_builtin(__builtin_amdgcn_exp2f)
  return __builtin_amdgcn_exp2f(x);
#else
  return __expf(x * 0.69314718f);
#endif
}

// ---------------------------------------------------------------- fused cast f32->bf16
__global__ __launch_bounds__(256) void castall(
    const float* __restrict__ x, const float* __restrict__ wq, const float* __restrict__ wk,
    const float* __restrict__ wv, const float* __restrict__ wp,
    __bf16* __restrict__ xb, __bf16* __restrict__ wqb, __bf16* __restrict__ wkb,
    __bf16* __restrict__ wvb, __bf16* __restrict__ wpb) {
  const int bid = blockIdx.x;
  const float* src;
  __bf16* dst;
  if (bid < 8192)       { src = x  + (size_t)bid * 1024;           dst = xb  + (size_t)bid * 1024; }
  else if (bid < 9216)  { src = wq + (size_t)(bid - 8192) * 1024;  dst = wqb + (size_t)(bid - 8192) * 1024; }
  else if (bid < 10240) { src = wk + (size_t)(bid - 9216) * 1024;  dst = wkb + (size_t)(bid - 9216) * 1024; }
  else if (bid < 11264) { src = wv + (size_t)(bid - 10240) * 1024; dst = wvb + (size_t)(bid - 10240) * 1024; }
  else                  { src = wp + (size_t)(bid - 11264) * 1024; dst = wpb + (size_t)(bid - 11264) * 1024; }
  const int i = threadIdx.x * 4;
  float4 f = *reinterpret_cast<const float4*>(src + i);
  bf16x4 o;
  o[0] = (__bf16)f.x; o[1] = (__bf16)f.y; o[2] = (__bf16)f.z; o[3] = (__bf16)f.w;
  *reinterpret_cast<bf16x4*>(dst + i) = o;
}

// ---------------------------------------------------------------- async global->LDS
__device__ __forceinline__ void gload_lds16(const __bf16* g, __bf16* lds) {
  __builtin_amdgcn_global_load_lds(
      (const __attribute__((address_space(1))) void*)g,
      (__attribute__((address_space(3))) void*)lds, 16, 0, 0);
}

// ---------------------------------------------------------------- 8-phase GEMM, BM=256 x BN=128 (R12-proven)
#define ST_A41(BUFO, KT, HH)                                                          \
  do {                                                                                \
    const __bf16* s0_ = Agp + (size_t)(m0 + (HH) * 128 + srow) * 1024 + (KT) * 64 + sswz; \
    gload_lds16(s0_, LDSb + (BUFO) + (HH) * 8192 + w * 1024);                         \
    gload_lds16(s0_ + 8 * 1024, LDSb + (BUFO) + (HH) * 8192 + w * 1024 + 512);        \
  } while (0)
#define ST_B41(BUFO, KT)                                                              \
  do {                                                                                \
    const __bf16* s0_ = Bgp + (size_t)(n0 + srow) * 1024 + (KT) * 64 + sswz;          \
    gload_lds16(s0_, LDSb + 32768 + (BUFO) + w * 1024);                               \
    gload_lds16(s0_ + 8 * 1024, LDSb + 32768 + (BUFO) + w * 1024 + 512);              \
  } while (0)
#define RDA41(M, KK) (*reinterpret_cast<const bf16x8*>(                               \
    LDSb + bufoA + (wr * 64 + (M) * 16 + lr) * 64 + (((KK) * 32 + lg * 8) ^ ((lr & 7) * 8))))
#define RDB41(N, KK) (*reinterpret_cast<const bf16x8*>(                               \
    LDSb + 32768 + bufoB + (wc * 64 + (N) * 16 + lr) * 64 + (((KK) * 32 + lg * 8) ^ ((lr & 7) * 8))))

#define GEMM8_KLOOP_41                                                                \
  ST_A41(0, 0, 0); ST_A41(0, 0, 1); ST_B41(0, 0);                                     \
  __builtin_amdgcn_sched_barrier(0);                                                  \
  asm volatile("s_waitcnt vmcnt(0)" ::: "memory");                                    \
  __builtin_amdgcn_s_barrier();                                                       \
  __builtin_amdgcn_sched_barrier(0);                                                  \
  for (int t = 0; t < 16; ++t) {                                                      \
    const int bufoA = (t & 1) * 16384;                                                \
    const int bufoB = (t & 1) * 8192;                                                 \
    const int nboA = ((t + 1) & 1) * 16384;                                           \
    const int nboB = ((t + 1) & 1) * 8192;                                            \
    const bool st = t < 15;                                                           \
    afA[0][0] = RDA41(0, 0); afA[0][1] = RDA41(0, 1);                                 \
    afA[1][0] = RDA41(1, 0); afA[1][1] = RDA41(1, 1);                                 \
    bfA[0][0] = RDB41(0, 0); bfA[0][1] = RDB41(0, 1);                                 \
    bfA[1][0] = RDB41(1, 0); bfA[1][1] = RDB41(1, 1);                                 \
    if (st) ST_A41(nboA, t + 1, 0);                                                   \
    __builtin_amdgcn_s_setprio(1);                                                    \
    _Pragma("unroll")                                                                 \
    for (int kk = 0; kk < 2; ++kk)                                                    \
      _Pragma("unroll")                                                               \
      for (int m = 0; m < 2; ++m) {                                                   \
        acc[m][0] = __builtin_amdgcn_mfma_f32_16x16x32_bf16(afA[m][kk], bfA[0][kk], acc[m][0], 0, 0, 0); \
        acc[m][1] = __builtin_amdgcn_mfma_f32_16x16x32_bf16(afA[m][kk], bfA[1][kk], acc[m][1], 0, 0, 0); \
      }                                                                               \
    __builtin_amdgcn_s_setprio(0);                                                    \
    __builtin_amdgcn_s_barrier();                                                     \
    bfB[0][0] = RDB41(2, 0); bfB[0][1] = RDB41(2, 1);                                 \
    bfB[1][0] = RDB41(3, 0); bfB[1][1] = RDB41(3, 1);                                 \
    if (st) ST_A41(nboA, t + 1, 1);                                                   \
    __builtin_amdgcn_s_setprio(1);                                                    \
    _Pragma("unroll")                                                                 \
    for (int kk = 0; kk < 2; ++kk)                                                    \
      _Pragma("unroll")                                                               \
      for (int m = 0; m < 2; ++m) {                                                   \
        acc[m][2] = __builtin_amdgcn_mfma_f32_16x16x32_bf16(afA[m][kk], bfB[0][kk], acc[m][2], 0, 0, 0); \
        acc[m][3] = __builtin_amdgcn_mfma_f32_16x16x32_bf16(afA[m][kk], bfB[1][kk], acc[m][3], 0, 0, 0); \
      }                                                                               \
    __builtin_amdgcn_s_setprio(0);                                                    \
    __builtin_amdgcn_s_barrier();                                                     \
    afB[0][0] = RDA41(2, 0); afB[0][1] = RDA41(2, 1);                                 \
    afB[1][0] = RDA41(3, 0); afB[1][1] = RDA41(3, 1);                                 \
    if (st) ST_B41(nboB, t + 1);                                                      \
    __builtin_amdgcn_s_setprio(1);                                                    \
    _Pragma("unroll")                                                                 \
    for (int kk = 0; kk < 2; ++kk)                                                    \
      _Pragma("unroll")                                                               \
      for (int m = 0; m < 2; ++m) {                                                   \
        acc[m + 2][0] = __builtin_amdgcn_mfma_f32_16x16x32_bf16(afB[m][kk], bfA[0][kk], acc[m + 2][0], 0, 0, 0); \
        acc[m + 2][1] = __builtin_amdgcn_mfma_f32_16x16x32_bf16(afB[m][kk], bfA[1][kk], acc[m + 2][1], 0, 0, 0); \
      }                                                                               \
    __builtin_amdgcn_s_setprio(0);                                                    \
    __builtin_amdgcn_s_barrier();                                                     \
    __builtin_amdgcn_s_setprio(1);                                                    \
    _Pragma("unroll")                                                                 \
    for (int kk = 0; kk < 2; ++kk)                                                    \
      _Pragma("unroll")                                                               \
      for (int m = 0; m < 2; ++m) {                                                   \
        acc[m + 2][2] = __builtin_amdgcn_mfma_f32_16x16x32_bf16(afB[m][kk], bfB[0][kk], acc[m + 2][2], 0, 0, 0); \
        acc[m + 2][3] = __builtin_amdgcn_mfma_f32_16x16x32_bf16(afB[m][kk], bfB[1][kk], acc[m + 2][3], 0, 0, 0); \
      }                                                                               \
    __builtin_amdgcn_s_setprio(0);                                                    \
    __builtin_amdgcn_sched_barrier(0);                                                \
    asm volatile("s_waitcnt vmcnt(0)" ::: "memory");                                  \
    __builtin_amdgcn_s_barrier();                                                     \
    __builtin_amdgcn_sched_barrier(0);                                                \
  }

// ---------------------------------------------------------------- fused QKV GEMM (256x128, 768 blocks)
__global__ __launch_bounds__(512, 2) void gemm_qkv8(
    const __bf16* __restrict__ Agp, const __bf16* __restrict__ Bgp,
    __bf16* __restrict__ qf, __bf16* __restrict__ kf, __bf16* __restrict__ vf) {
  __shared__ __bf16 LDSb[49152];
  const int tid = threadIdx.x;
  const int w = tid >> 6, l = tid & 63;
  const int wr = w >> 1, wc = w & 1;
  const int lr = l & 15, lg = l >> 4;
  int lin = blockIdx.y * 24 + blockIdx.x;
  lin = (lin & 7) * 96 + (lin >> 3);
  const int bx = lin % 24, by = lin / 24;
  const int m0 = by * 256, n0 = bx * 128;
  const int srow = w * 16 + (l >> 3);
  const int sswz = ((l & 7) ^ ((l >> 3) & 7)) * 8;

  f32x4 acc[4][4] = {};
  bf16x8 afA[2][2], afB[2][2], bfA[2][2], bfB[2][2];

  GEMM8_KLOOP_41

  __bf16* wl = LDSb + w * 4096;
  const int colb = n0 + wc * 64;
  const int mat = colb >> 10;
  const int h = (colb >> 6) & 15;
  const int b = m0 >> 11;
  const float qsc = (mat == 0) ? 0.04508422f : 1.0f;  // C^-0.5 * log2(e)
#pragma unroll
  for (int mi = 0; mi < 4; ++mi) {
    const int rt = mi >> 1;
#pragma unroll
    for (int n = 0; n < 4; ++n) {
      const int d = n * 16 + lr;
#pragma unroll
      for (int j = 0; j < 4; ++j) {
        const int rowloc = (mi & 1) * 16 + lg * 4 + j;
        int off;
        if (mat < 2)
          off = ((d >> 4) & 3) * 512 + ((d >> 3) & 1) * 256 + rowloc * 8 + (d & 7);
        else
          off = (d >> 5) * 1024 + ((rowloc >> 4) & 1) * 512 + ((rowloc >> 3) & 1) * 256 +
                (d & 31) * 8 + (rowloc & 7);
        wl[rt * 2048 + off] = (__bf16)(acc[mi][n][j] * qsc);
      }
    }
  }
  __bf16* dstbase = (mat == 0 ? qf : mat == 1 ? kf : vf) + (size_t)(b * 16 + h) * BH_STRIDE_;
  const int rt0 = ((m0 + wr * 64) >> 5) & 63;
#pragma unroll
  for (int rt = 0; rt < 2; ++rt)
#pragma unroll
    for (int c = 0; c < 4; ++c) {
      const bf16x8 vchunk = *reinterpret_cast<const bf16x8*>(wl + rt * 2048 + c * 512 + l * 8);
      *reinterpret_cast<bf16x8*>(dstbase + (size_t)(rt0 + rt) * TILE_ELEMS_ + c * 512 + l * 8) = vchunk;
    }
}

// ---------------------------------------------------------------- proj GEMM (256x128, 256 blocks)
__global__ __launch_bounds__(512, 2) void gemm_proj8(
    const __bf16* __restrict__ Agp, const __bf16* __restrict__ Bgp,
    float* __restrict__ out, const float* __restrict__ bias) {
  __shared__ __bf16 LDSb[49152];
  const int tid = threadIdx.x;
  const int w = tid >> 6, l = tid & 63;
  const int wr = w >> 1, wc = w & 1;
  const int lr = l & 15, lg = l >> 4;
  int lin = blockIdx.y * 8 + blockIdx.x;
  lin = (lin & 7) * 32 + (lin >> 3);
  const int bx = lin & 7, by = lin >> 3;
  const int m0 = by * 256, n0 = bx * 128;
  const int srow = w * 16 + (l >> 3);
  const int sswz = ((l & 7) ^ ((l >> 3) & 7)) * 8;

  f32x4 acc[4][4] = {};
  bf16x8 afA[2][2], afB[2][2], bfA[2][2], bfB[2][2];

  GEMM8_KLOOP_41

  const int colb = n0 + wc * 64;
#pragma unroll
  for (int mi = 0; mi < 4; ++mi) {
    const int row = m0 + wr * 64 + mi * 16 + lg * 4;
#pragma unroll
    for (int n = 0; n < 4; ++n) {
      const int col = colb + n * 16 + lr;
      const float bv = bias[col];
#pragma unroll
      for (int j = 0; j < 4; ++j)
        out[(size_t)(row + j) * 1024 + col] = acc[mi][n][j] + bv;
    }
  }
}

// ---------------------------------------------------------------- helpers
__device__ __forceinline__ unsigned pk2(float a, float b) {
  const unsigned short ua = __builtin_bit_cast(unsigned short, (__bf16)a);
  const unsigned short ub = __builtin_bit_cast(unsigned short, (__bf16)b);
  return (unsigned)ua | ((unsigned)ub << 16);
}

// P^T word exchange (R14-verified): permlane32_swap(X, Y) -> {w0, w2}.
__device__ __forceinline__ void exch2(unsigned X, unsigned Y, int hi,
                                      unsigned& w0, unsigned& w2) {
#if __has_builtin(__builtin_amdgcn_permlane32_swap)
  auto r = __builtin_amdgcn_permlane32_swap(X, Y, false, false);
  w0 = r[0];
  w2 = r[1];
#else
  const unsigned sX = __shfl_xor(X, 32);
  const unsigned sY = __shfl_xor(Y, 32);
  w0 = hi ? sY : X;
  w2 = hi ? Y : sX;
#endif
}

// ---------------------------------------------------------------- flash attention v14 (R16-proven, final)
// 256-thr blocks (4 waves), one q-pair per wave {qx, 63-qx} => uniform 65
// tiles/wave, zero LDS/barriers, serial tile loop with A/B register prefetch,
// XCD affinity, permlane exch2, Q pre-scaled (exp2 direct). No setprio.
#define LOADKV(SFX, TT)                                                          \
  do {                                                                           \
    const __bf16* kp_ = kfb + (size_t)(TT) * TILE_ELEMS_ + lx8;                  \
    k##SFX##0 = *reinterpret_cast<const bf16x8*>(kp_);                           \
    k##SFX##1 = *reinterpret_cast<const bf16x8*>(kp_ + 512);                     \
    k##SFX##2 = *reinterpret_cast<const bf16x8*>(kp_ + 1024);                    \
    k##SFX##3 = *reinterpret_cast<const bf16x8*>(kp_ + 1536);                    \
    const __bf16* vp_ = vfb + (size_t)(TT) * TILE_ELEMS_ + lx8;                  \
    v##SFX##0 = *reinterpret_cast<const bf16x8*>(vp_);                           \
    v##SFX##1 = *reinterpret_cast<const bf16x8*>(vp_ + 512);                     \
    v##SFX##2 = *reinterpret_cast<const bf16x8*>(vp_ + 1024);                    \
    v##SFX##3 = *reinterpret_cast<const bf16x8*>(vp_ + 1536);                    \
  } while (0)

#define TILE(SFX, MASKED)                                                        \
  do {                                                                           \
    f32x16 s = {};                                                               \
    s = __builtin_amdgcn_mfma_f32_32x32x16_bf16(k##SFX##0, qf[0], s, 0, 0, 0);   \
    s = __builtin_amdgcn_mfma_f32_32x32x16_bf16(k##SFX##1, qf[1], s, 0, 0, 0);   \
    s = __builtin_amdgcn_mfma_f32_32x32x16_bf16(k##SFX##2, qf[2], s, 0, 0, 0);   \
    s = __builtin_amdgcn_mfma_f32_32x32x16_bf16(k##SFX##3, qf[3], s, 0, 0, 0);   \
    float sv[16];                                                                \
    _Pragma("unroll") for (int r = 0; r < 16; ++r) sv[r] = s[r];                 \
    if (MASKED) {                                                                \
      _Pragma("unroll") for (int r = 0; r < 16; ++r) {                           \
        const int kvloc = (r & 3) + 8 * (r >> 2) + 4 * hi;                       \
        sv[r] = (kvloc <= lane31) ? sv[r] : -1e30f;                              \
      }                                                                          \
    }                                                                            \
    _Pragma("unroll") for (int r = 0; r < 16; ++r) sv[r] = fexp2(sv[r]);         \
    unsigned pwv[8];                                                             \
    _Pragma("unroll") for (int ks = 0; ks < 2; ++ks) {                           \
      const unsigned X0 = pk2(sv[ks * 8 + 0], sv[ks * 8 + 1]);                   \
      const unsigned X1 = pk2(sv[ks * 8 + 2], sv[ks * 8 + 3]);                   \
      const unsigned Y0 = pk2(sv[ks * 8 + 4], sv[ks * 8 + 5]);                   \
      const unsigned Y1 = pk2(sv[ks * 8 + 6], sv[ks * 8 + 7]);                   \
      exch2(X0, Y0, hi, pwv[ks * 4 + 0], pwv[ks * 4 + 2]);                       \
      exch2(X1, Y1, hi, pwv[ks * 4 + 1], pwv[ks * 4 + 3]);                       \
    }                                                                            \
    const uint4v u0 = {pwv[0], pwv[1], pwv[2], pwv[3]};                          \
    const uint4v u1 = {pwv[4], pwv[5], pwv[6], pwv[7]};                          \
    const bf16x8 pf0 = __builtin_bit_cast(bf16x8, u0);                           \
    const bf16x8 pf1 = __builtin_bit_cast(bf16x8, u1);                           \
    acc0 = __builtin_amdgcn_mfma_f32_32x32x16_bf16(v##SFX##0, pf0, acc0, 0, 0, 0); \
    acc0 = __builtin_amdgcn_mfma_f32_32x32x16_bf16(v##SFX##1, pf1, acc0, 0, 0, 0); \
    acc1 = __builtin_amdgcn_mfma_f32_32x32x16_bf16(v##SFX##2, pf0, acc1, 0, 0, 0); \
    acc1 = __builtin_amdgcn_mfma_f32_32x32x16_bf16(v##SFX##3, pf1, acc1, 0, 0, 0); \
    float b8[8];                                                                 \
    _Pragma("unroll") for (int r = 0; r < 8; ++r) b8[r] = sv[2 * r] + sv[2 * r + 1]; \
    _Pragma("unroll") for (int r = 0; r < 4; ++r) b8[r] = b8[2 * r] + b8[2 * r + 1]; \
    l_run += (b8[0] + b8[1]) + (b8[2] + b8[3]);                                  \
  } while (0)

__global__ __launch_bounds__(256) void attn_fwd(const __bf16* __restrict__ qfr,
                                                const __bf16* __restrict__ kfr,
                                                const __bf16* __restrict__ vfr,
                                                __bf16* __restrict__ ao) {
  const int tid = threadIdx.x;
  const int w = tid >> 6, l = tid & 63;
  const int lane31 = l & 31, hi = l >> 5;
  const int bh = blockIdx.x & 63;   // XCD affinity: lin%8 == bh%8 (R11-proven)
  const int qi = blockIdx.x >> 6;   // 0..7
  const int b = bh >> 4;
  const int qx = qi * 4 + w;        // 0..31; paired with 63-qx => 65 tiles/wave
  const size_t rowbase = (size_t)b * T_;
  const int hoff = (bh & 15) * D_;
  const int lx8 = l * 8;
  const __bf16* qfb = qfr + (size_t)bh * BH_STRIDE_;
  const __bf16* kfb = kfr + (size_t)bh * BH_STRIDE_;
  const __bf16* vfb = vfr + (size_t)bh * BH_STRIDE_;

  for (int phase = 0; phase < 2; ++phase) {
    const int qg = (phase ? 63 - qx : qx) * 32;
    const int ntiles = (qg >> 5) + 1;

    bf16x8 qf[4];
    {
      const __bf16* qp = qfb + (size_t)(qg >> 5) * TILE_ELEMS_ + lx8;
#pragma unroll
      for (int t4 = 0; t4 < 4; ++t4) qf[t4] = *reinterpret_cast<const bf16x8*>(qp + t4 * 512);
    }

    f32x16 acc0 = {};
    f32x16 acc1 = {};
    float l_run = 0.f;

    bf16x8 kA0, kA1, kA2, kA3, vA0, vA1, vA2, vA3;
    bf16x8 kB0, kB1, kB2, kB3, vB0, vB1, vB2, vB3;

    LOADKV(A, 0);
    int t = 0;
    for (; t + 1 < ntiles; ++t) {
      if ((t & 1) == 0) { LOADKV(B, t + 1); TILE(A, false); }
      else              { LOADKV(A, t + 1); TILE(B, false); }
    }
    if ((t & 1) == 0) TILE(A, true);
    else              TILE(B, true);

    // combine the two kv-halves held by partner lanes
    l_run += __shfl_xor(l_run, 32);

    // epilogue: O[q][d] = O^T[d][q]/l ; d = dblk*32 + qd*8 + hi*4 + j
    const float rl = 1.0f / l_run;
    __bf16* op = ao + (rowbase + qg + lane31) * C_ + hoff + hi * 4;
#pragma unroll
    for (int dblk = 0; dblk < 2; ++dblk)
#pragma unroll
      for (int qd = 0; qd < 4; ++qd) {
        bf16x4 ov;
#pragma unroll
        for (int j = 0; j < 4; ++j) {
          const float av = (dblk == 0) ? acc0[qd * 4 + j] : acc1[qd * 4 + j];
          ov[j] = (__bf16)(av * rl);
        }
        *reinterpret_cast<bf16x4*>(op + dblk * 32 + qd * 8) = ov;
      }
  }
}

// ---------------------------------------------------------------- launch
extern "C" void kernel_launch(void* const* d_in, const int* in_sizes, int n_in,
                              void* d_out, int out_size, void* d_ws, size_t ws_size,
                              hipStream_t stream) {
  const float* x  = (const float*)d_in[0];
  const float* Wq = (const float*)d_in[1];
  const float* Wk = (const float*)d_in[2];
  const float* Wv = (const float*)d_in[3];
  const float* Wp = (const float*)d_in[4];
  const float* bp = (const float*)d_in[5];
  float* out = (float*)d_out;

  const int NX = B_ * T_ * C_;
  const int NW = C_ * C_;

  __bf16* xb  = (__bf16*)d_ws;
  __bf16* wqb = xb + NX;
  __bf16* wkb = wqb + NW;
  __bf16* wvb = wkb + NW;
  __bf16* wpb = wvb + NW;
  __bf16* qf  = wpb + NW;
  __bf16* kf  = qf + NX;
  __bf16* vf  = kf + NX;
  __bf16* aob = xb;  // xb dead after gemm_qkv8

  castall<<<12288, 256, 0, stream>>>(x, Wq, Wk, Wv, Wp, xb, wqb, wkb, wvb, wpb);

  gemm_qkv8<<<dim3(24, 32), 512, 0, stream>>>(xb, wqb, qf, kf, vf);
  attn_fwd<<<512, 256, 0, stream>>>(qf, kf, vf, aob);
  gemm_proj8<<<dim3(8, 32), 512, 0, stream>>>(aob, wpb, out, bp);
}